// Round 14
// baseline (88.226 us; speedup 1.0000x reference)
//
#include <hip/hip_runtime.h>

// FeatureEmbedder: out[b, f*64+d] = relu(x[b,f] * W[f,d] + b[f,d])
// x: [16384, 128] f32, W: [128, 64] f32, b: [128, 64] f32
// out: [16384, 8192] f32  (512 MB -> HBM-write-bound)
//
// R14: R12 (nt x block-linear, 85.3 us = best) with 128 blocks instead of
// 64 — single-variable test of per-CU store-issue limiting. R12 asked ~94
// GB/s of store issue from each of 64 CUs (~half the plausible per-CU write
// port rate, shared with x-load + LDS traffic); the 6.7 TB/s fill spreads
// the same aggregate over ~4x more CUs. 128 blocks x 1024 threads: block b
// owns the contiguous 4 MB region rows [128b, 128b+128), swept in 4 slabs
// of 32 rows. Everything else identical to R12: nt stores, 2 x 16 KB LDS
// double-buffered x slabs, 2 hoisted W/b pairs, broadcast ds_reads,
// __syncthreads phase boundaries (R13 proved barrier drains are hidden).
// Pre-commit: win -> keep + declare roofline; null/regress -> revert to
// R12 and declare roofline.

#define BATCH 16384
#define NFEAT 128
#define EMBD  64
#define ROW4  (NFEAT * EMBD / 4)   // 2048 float4 per output row
#define RPB   128                  // rows per block
#define SROWS 32                   // rows per slab

typedef float vfloat4 __attribute__((ext_vector_type(4)));

__global__ __launch_bounds__(1024) void feature_embed_kernel(
    const vfloat4* __restrict__ x4,
    const vfloat4* __restrict__ W4,
    const vfloat4* __restrict__ B4,
    vfloat4* __restrict__ out4) {

    __shared__ float xs[2][SROWS * NFEAT];  // 2 x 16 KB slab buffers

    const int tid = threadIdx.x;          // 0..1023
    const int b   = blockIdx.x;           // 0..127

    // Thread's columns: col4 = j*1024 + tid, j = 0..1. Hoist W/b.
    vfloat4 wv[2], bv[2];
    wv[0] = W4[tid];        wv[1] = W4[1024 + tid];
    bv[0] = B4[tid];        bv[1] = B4[1024 + tid];

    // Block owns x rows [128b, 128b+128) = 4096 float4: 4 slabs x 1024.
    const vfloat4* xb = x4 + b * (RPB * NFEAT / 4);

    ((vfloat4*)xs[0])[tid] = xb[tid];     // stage slab 0 (1 float4/thread)
    __syncthreads();

    const int fs = tid >> 4;              // feature sub-index, 0..63
    vfloat4* outb = out4 + (size_t)b * RPB * ROW4;  // block's 4 MB region

    for (int s = 0; s < 4; ++s) {
        // Prefetch next slab into the other buffer (1 load / 64 stores).
        if (s < 3)
            ((vfloat4*)xs[(s + 1) & 1])[tid] = xb[(s + 1) * 1024 + tid];

        const float* xsl = xs[s & 1];
        vfloat4* outs = outb + s * SROWS * ROW4;

        #pragma unroll 4
        for (int r = 0; r < SROWS; ++r) {
            const float* xr = xsl + r * NFEAT;
            vfloat4* outr = outs + r * ROW4 + tid;
            #pragma unroll
            for (int j = 0; j < 2; ++j) {
                const float xv = xr[j * 64 + fs];   // ds_read broadcast
                vfloat4 o;
                o.x = fmaxf(fmaf(xv, wv[j].x, bv[j].x), 0.0f);
                o.y = fmaxf(fmaf(xv, wv[j].y, bv[j].y), 0.0f);
                o.z = fmaxf(fmaf(xv, wv[j].z, bv[j].z), 0.0f);
                o.w = fmaxf(fmaf(xv, wv[j].w, bv[j].w), 0.0f);
                // Streaming store: linear sweep, no L2 allocation.
                __builtin_nontemporal_store(o, &outr[j * 1024]);
            }
        }
        __syncthreads();  // prefetch visible; buffer free for next overwrite
    }
}

extern "C" void kernel_launch(void* const* d_in, const int* in_sizes, int n_in,
                              void* d_out, int out_size, void* d_ws, size_t ws_size,
                              hipStream_t stream) {
    const vfloat4* x4 = (const vfloat4*)d_in[0];
    const vfloat4* W4 = (const vfloat4*)d_in[1];
    const vfloat4* B4 = (const vfloat4*)d_in[2];
    vfloat4* out4     = (vfloat4*)d_out;

    // 128 blocks x 1024 threads; block b writes rows [128b, 128b+128) linearly.
    feature_embed_kernel<<<128, 1024, 0, stream>>>(x4, W4, B4, out4);
}

// Round 15
// 85.038 us; speedup vs baseline: 1.0375x; 1.0375x over previous
//
#include <hip/hip_runtime.h>

// FeatureEmbedder: out[b, f*64+d] = relu(x[b,f] * W[f,d] + b[f,d])
// x: [16384, 128] f32, W: [128, 64] f32, b: [128, 64] f32
// out: [16384, 8192] f32  (512 MB -> HBM-write-bound)
//
// FINAL (= R12, best at 85.3 us ~= 6.1 TB/s effective, ~92% of the
// device's own fillBuffer streaming rate). Key findings of the session:
//  - nt (no-L2-allocate) stores x block-linear layout is the winning cell:
//    store order reaches DRAM as issued instead of L2-eviction-scrambled
//    (+14% vs cached stores; nt on a scattered layout is null, R3).
//  - 64 concurrent write streams (64 blocks, 8 MB contiguous region each)
//    beats 128/256/512/2048 streams (R14/R8/R5/R0 ladder).
//  - x staged in LDS keeps the vmcnt FIFO pure-store (direct-x loads
//    serialize against store acks: +9 us, R9).
//  - Barrier drains at phase boundaries are hidden by 16-wave TLP (R13).
// Structure: 64 blocks x 1024 threads; block b sweeps rows [256b, 256b+256)
// (8 MB) in 8 slabs of 32 rows; x slab double-buffered in LDS (1 float4
// load/thread/slab vs 64 stores); 2 hoisted W/b pairs; conflict-free
// 16-lane broadcast ds_reads; pure nt-store stream.

#define BATCH 16384
#define NFEAT 128
#define EMBD  64
#define ROW4  (NFEAT * EMBD / 4)   // 2048 float4 per output row

typedef float vfloat4 __attribute__((ext_vector_type(4)));

__global__ __launch_bounds__(1024) void feature_embed_kernel(
    const vfloat4* __restrict__ x4,
    const vfloat4* __restrict__ W4,
    const vfloat4* __restrict__ B4,
    vfloat4* __restrict__ out4) {

    __shared__ float xs[2][32 * NFEAT];   // 2 x 16 KB slab buffers

    const int tid = threadIdx.x;          // 0..1023
    const int b   = blockIdx.x;           // 0..63

    // Thread's columns: col4 = j*1024 + tid, j = 0..1. Hoist W/b.
    vfloat4 wv[2], bv[2];
    wv[0] = W4[tid];        wv[1] = W4[1024 + tid];
    bv[0] = B4[tid];        bv[1] = B4[1024 + tid];

    // Block owns x rows [256b, 256b+256): 8 slabs x 32 rows.
    const vfloat4* xb = x4 + b * (256 * NFEAT / 4);

    ((vfloat4*)xs[0])[tid] = xb[tid];     // stage slab 0
    __syncthreads();

    const int fs = tid >> 4;              // feature sub-index, 0..63
    vfloat4* outb = out4 + b * 256 * ROW4;  // this block's 8 MB region

    for (int s = 0; s < 8; ++s) {
        // Prefetch next slab into the other buffer (overlaps with stores).
        if (s < 7)
            ((vfloat4*)xs[(s + 1) & 1])[tid] = xb[(s + 1) * 1024 + tid];

        const float* xsl = xs[s & 1];
        vfloat4* outs = outb + s * 32 * ROW4;

        #pragma unroll 4
        for (int r = 0; r < 32; ++r) {
            const float* xr = xsl + r * NFEAT;
            vfloat4* outr = outs + r * ROW4 + tid;
            #pragma unroll
            for (int j = 0; j < 2; ++j) {
                const float xv = xr[j * 64 + fs];   // ds_read broadcast
                vfloat4 o;
                o.x = fmaxf(fmaf(xv, wv[j].x, bv[j].x), 0.0f);
                o.y = fmaxf(fmaf(xv, wv[j].y, bv[j].y), 0.0f);
                o.z = fmaxf(fmaf(xv, wv[j].z, bv[j].z), 0.0f);
                o.w = fmaxf(fmaf(xv, wv[j].w, bv[j].w), 0.0f);
                // Streaming store: linear sweep, no L2 allocation.
                __builtin_nontemporal_store(o, &outr[j * 1024]);
            }
        }
        __syncthreads();  // prefetch visible; buffer free for next overwrite
    }
}

extern "C" void kernel_launch(void* const* d_in, const int* in_sizes, int n_in,
                              void* d_out, int out_size, void* d_ws, size_t ws_size,
                              hipStream_t stream) {
    const vfloat4* x4 = (const vfloat4*)d_in[0];
    const vfloat4* W4 = (const vfloat4*)d_in[1];
    const vfloat4* B4 = (const vfloat4*)d_in[2];
    vfloat4* out4     = (vfloat4*)d_out;

    // 64 blocks x 1024 threads; block b writes rows [256b, 256b+256) linearly.
    feature_embed_kernel<<<64, 1024, 0, stream>>>(x4, W4, B4, out4);
}